// Round 1
// baseline (832.581 us; speedup 1.0000x reference)
//
#include <hip/hip_runtime.h>
#include <float.h>

#define HH 128
#define NROWS 32768
#define KCODES 4096
#define BM 64
#define BN 64

// XOR-swizzled LDS layouts (float indices).
// zs: 64 rows x 128 floats, quad (row, hq) at row*128 + (hq ^ (row&7))*4
// ws: 128 h x 64 codes (transposed), quad (h, cq) at h*64 + (cq ^ (h&15))*4
__device__ __forceinline__ int zs_off(int row, int hq) {
    return (row << 7) + ((hq ^ (row & 7)) << 2);
}
__device__ __forceinline__ int ws_off(int h, int cq) {
    return (h << 6) + ((cq ^ (h & 15)) << 2);
}

__global__ __launch_bounds__(256) void vq_prep(const float* __restrict__ w,
                                               float* __restrict__ wsq,
                                               float* __restrict__ loss_slot) {
    int c = blockIdx.x * 256 + threadIdx.x;
    if (c == 0) loss_slot[0] = 0.0f;  // d_out is poisoned 0xAA each launch
    if (c < KCODES) {
        const float4* row = reinterpret_cast<const float4*>(w + (size_t)c * HH);
        float s = 0.0f;
#pragma unroll
        for (int i = 0; i < HH / 4; ++i) {
            float4 v = row[i];
            s = fmaf(v.x, v.x, s);
            s = fmaf(v.y, v.y, s);
            s = fmaf(v.z, v.z, s);
            s = fmaf(v.w, v.w, s);
        }
        wsq[c] = s;
    }
}

__global__ __launch_bounds__(256, 2) void vq_main(const float* __restrict__ z,
                                                  const float* __restrict__ w,
                                                  const float* __restrict__ wsq,
                                                  float* __restrict__ out_zq,
                                                  float* __restrict__ out_idx,
                                                  float* __restrict__ out_loss) {
    __shared__ float zsm[BM * HH];            // 32 KB, live whole kernel
    __shared__ union {                        // 32 KB, ws reused by epilogue
        float ws[HH * BN];
        struct { int bidx[BM]; float lred[4]; } ep;
    } u;

    const int t  = threadIdx.x;
    const int tx = t & 15;        // code group (4 codes)
    const int ty = t >> 4;        // row group (4 rows)
    const int rowBase = blockIdx.x * BM;
    const int cw = t & 63;        // staging: code within tile
    const int jw = t >> 6;        // staging: h4 block

    // stage z tile once (coalesced float4 reads)
    {
        const float4* zg = reinterpret_cast<const float4*>(z + (size_t)rowBase * HH);
#pragma unroll
        for (int i = 0; i < 8; ++i) {
            int g = t + i * 256;          // 0..2047
            int r = g >> 5;
            int c4 = g & 31;
            float4 v = zg[g];
            *reinterpret_cast<float4*>(&zsm[zs_off(r, c4)]) = v;
        }
    }

    float best[4] = {FLT_MAX, FLT_MAX, FLT_MAX, FLT_MAX};
    int   bidx[4] = {0, 0, 0, 0};

    for (int k0 = 0; k0 < KCODES; k0 += BN) {
        __syncthreads();  // prev tile consumed (and z-stage visible after next sync)
        // stage w tile transposed: each thread owns one code row, 128B-contiguous
        // chunk (intra-thread 64B-line locality); LDS scalar writes land at the
        // same h across a wave -> consecutive banks, conflict-free.
        {
            const float4* wrow = reinterpret_cast<const float4*>(w + (size_t)(k0 + cw) * HH);
            const int cq = cw >> 2, ce = cw & 3;
#pragma unroll
            for (int q = 0; q < 8; ++q) {
                int h4 = (jw << 3) + q;
                float4 v = wrow[h4];
                int h = h4 << 2;
                u.ws[ws_off(h + 0, cq) + ce] = v.x;
                u.ws[ws_off(h + 1, cq) + ce] = v.y;
                u.ws[ws_off(h + 2, cq) + ce] = v.z;
                u.ws[ws_off(h + 3, cq) + ce] = v.w;
            }
        }
        float4 wq4 = *reinterpret_cast<const float4*>(wsq + k0 + (tx << 2));
        __syncthreads();

        float acc[4][4] = {};
#pragma unroll 8
        for (int h = 0; h < HH; h += 4) {
            float4 wf0 = *reinterpret_cast<const float4*>(&u.ws[ws_off(h + 0, tx)]);
            float4 wf1 = *reinterpret_cast<const float4*>(&u.ws[ws_off(h + 1, tx)]);
            float4 wf2 = *reinterpret_cast<const float4*>(&u.ws[ws_off(h + 2, tx)]);
            float4 wf3 = *reinterpret_cast<const float4*>(&u.ws[ws_off(h + 3, tx)]);
#define VQ_ACC(r)                                                             \
            {                                                                 \
                float4 zf = *reinterpret_cast<const float4*>(                 \
                    &zsm[zs_off((ty << 2) + (r), h >> 2)]);                   \
                acc[r][0] = fmaf(zf.x, wf0.x, acc[r][0]);                     \
                acc[r][0] = fmaf(zf.y, wf1.x, acc[r][0]);                     \
                acc[r][0] = fmaf(zf.z, wf2.x, acc[r][0]);                     \
                acc[r][0] = fmaf(zf.w, wf3.x, acc[r][0]);                     \
                acc[r][1] = fmaf(zf.x, wf0.y, acc[r][1]);                     \
                acc[r][1] = fmaf(zf.y, wf1.y, acc[r][1]);                     \
                acc[r][1] = fmaf(zf.z, wf2.y, acc[r][1]);                     \
                acc[r][1] = fmaf(zf.w, wf3.y, acc[r][1]);                     \
                acc[r][2] = fmaf(zf.x, wf0.z, acc[r][2]);                     \
                acc[r][2] = fmaf(zf.y, wf1.z, acc[r][2]);                     \
                acc[r][2] = fmaf(zf.z, wf2.z, acc[r][2]);                     \
                acc[r][2] = fmaf(zf.w, wf3.z, acc[r][2]);                     \
                acc[r][3] = fmaf(zf.x, wf0.w, acc[r][3]);                     \
                acc[r][3] = fmaf(zf.y, wf1.w, acc[r][3]);                     \
                acc[r][3] = fmaf(zf.z, wf2.w, acc[r][3]);                     \
                acc[r][3] = fmaf(zf.w, wf3.w, acc[r][3]);                     \
            }
            VQ_ACC(0) VQ_ACC(1) VQ_ACC(2) VQ_ACC(3)
#undef VQ_ACC
        }

        // score = ||w||^2 - 2*dot  (note: *2 is exact in fp32, matches np rounding)
        float wqa[4] = {wq4.x, wq4.y, wq4.z, wq4.w};
#pragma unroll
        for (int j = 0; j < 4; ++j) {
            int code = k0 + (tx << 2) + j;
#pragma unroll
            for (int r = 0; r < 4; ++r) {
                float s = fmaf(-2.0f, acc[r][j], wqa[j]);
                if (s < best[r]) { best[r] = s; bidx[r] = code; }  // strict < = first-min
            }
        }
    }

    // reduce across the 16 code-threads sharing each row (tx bits live in lane 0..3)
#pragma unroll
    for (int off = 1; off < 16; off <<= 1) {
#pragma unroll
        for (int r = 0; r < 4; ++r) {
            float os = __shfl_xor(best[r], off, 64);
            int   oi = __shfl_xor(bidx[r], off, 64);
            if (os < best[r] || (os == best[r] && oi < bidx[r])) {
                best[r] = os; bidx[r] = oi;
            }
        }
    }

    __syncthreads();  // everyone done reading u.ws before aliasing it
    if (tx == 0) {
#pragma unroll
        for (int r = 0; r < 4; ++r) u.ep.bidx[(ty << 2) + r] = bidx[r];
    }
    __syncthreads();

    if (t < BM) out_idx[rowBase + t] = (float)u.ep.bidx[t];

    // gather zq (codebook is L2-resident), write out, accumulate loss
    float lsum = 0.0f;
#pragma unroll
    for (int i = 0; i < 8; ++i) {
        int g = t + i * 256;
        int r = g >> 5;
        int c4 = g & 31;
        int code = u.ep.bidx[r];
        float4 wv = *reinterpret_cast<const float4*>(w + (size_t)code * HH + (c4 << 2));
        float4 zv = *reinterpret_cast<const float4*>(&zsm[zs_off(r, c4)]);
        float dx = wv.x - zv.x, dy = wv.y - zv.y, dz = wv.z - zv.z, dw = wv.w - zv.w;
        lsum = fmaf(dx, dx, lsum);
        lsum = fmaf(dy, dy, lsum);
        lsum = fmaf(dz, dz, lsum);
        lsum = fmaf(dw, dw, lsum);
        *reinterpret_cast<float4*>(out_zq + (size_t)(rowBase + r) * HH + (c4 << 2)) = wv;
    }
#pragma unroll
    for (int off = 1; off < 64; off <<= 1) lsum += __shfl_xor(lsum, off, 64);
    if ((t & 63) == 0) u.ep.lred[t >> 6] = lsum;
    __syncthreads();
    if (t == 0) {
        float total = u.ep.lred[0] + u.ep.lred[1] + u.ep.lred[2] + u.ep.lred[3];
        // loss = (0.25 + 1.0) * mean((zq - z)^2) over N*H elements
        atomicAdd(out_loss, total * (1.25f / 4194304.0f));
    }
}

extern "C" void kernel_launch(void* const* d_in, const int* in_sizes, int n_in,
                              void* d_out, int out_size, void* d_ws, size_t ws_size,
                              hipStream_t stream) {
    (void)in_sizes; (void)n_in; (void)out_size; (void)ws_size;
    const float* z = (const float*)d_in[0];
    const float* w = (const float*)d_in[1];
    float* out      = (float*)d_out;
    float* out_zq   = out;                                  // N*H
    float* out_idx  = out + (size_t)NROWS * HH;             // N (as float)
    float* out_loss = out + (size_t)NROWS * HH + NROWS;     // 1
    float* wsq = (float*)d_ws;                              // 4096 floats

    vq_prep<<<KCODES / 256, 256, 0, stream>>>(w, wsq, out_loss);
    vq_main<<<NROWS / BM, 256, 0, stream>>>(z, w, wsq, out_zq, out_idx, out_loss);
}

// Round 2
// 200.415 us; speedup vs baseline: 4.1543x; 4.1543x over previous
//
#include <hip/hip_runtime.h>
#include <float.h>

#define HH 128
#define NROWS 32768
#define KCODES 4096
#define BM 64
#define BN 64

typedef _Float16 half8 __attribute__((ext_vector_type(8)));
typedef _Float16 half4_t __attribute__((ext_vector_type(4)));
typedef float floatx4 __attribute__((ext_vector_type(4)));

// LDS: 64 KB as ushort[32768]. Four fp16 planes, each 16 KB = 8192 halves:
//   ZH=0, ZL=8192, WH=16384, WL=24576
// Plane layout: unit(r, hu) — hu = h/8 in [0,16), r = row/code in [0,64).
// Element offset = (hu*64 + (r ^ (hu&7)))*8. The XOR swizzle makes every 8
// consecutive lanes of a b128 access cover all 32 banks (conflict-free).
#define ZH 0
#define ZL 8192
#define WH 16384
#define WL 24576

__device__ __forceinline__ int plane_off(int r, int hu) {
    return (hu << 6 | (r ^ (hu & 7))) << 3;
}

__global__ __launch_bounds__(256) void vq_prep(const float* __restrict__ w,
                                               float* __restrict__ wsq,
                                               float* __restrict__ loss_slot) {
    int c = blockIdx.x * 256 + threadIdx.x;
    if (c == 0) loss_slot[0] = 0.0f;  // d_out poisoned 0xAA each launch
    if (c < KCODES) {
        const float4* row = reinterpret_cast<const float4*>(w + (size_t)c * HH);
        float s = 0.0f;
#pragma unroll
        for (int i = 0; i < HH / 4; ++i) {
            float4 v = row[i];
            s = fmaf(v.x, v.x, s); s = fmaf(v.y, v.y, s);
            s = fmaf(v.z, v.z, s); s = fmaf(v.w, v.w, s);
        }
        wsq[c] = s;
    }
}

// Split-stage one 64-row fp32 tile (row stride 128 floats) into hi/lo fp16
// planes. Thread t pass p handles float4 #g: row g>>5, f4 g&31 (coalesced).
__device__ __forceinline__ void stage_tile(const float4* __restrict__ src4,
                                           ushort* lds, int hi_base, int lo_base,
                                           int t) {
#pragma unroll
    for (int p = 0; p < 8; ++p) {
        int g = p * 256 + t;
        int r = g >> 5, f4 = g & 31;
        int hu = f4 >> 1, half = f4 & 1;
        float4 v = src4[g];
        _Float16 h0 = (_Float16)v.x, h1 = (_Float16)v.y,
                 h2 = (_Float16)v.z, h3 = (_Float16)v.w;
        _Float16 l0 = (_Float16)(v.x - (float)h0);
        _Float16 l1 = (_Float16)(v.y - (float)h1);
        _Float16 l2 = (_Float16)(v.z - (float)h2);
        _Float16 l3 = (_Float16)(v.w - (float)h3);
        int off = plane_off(r, hu) + (half << 2);
        half4_t hv = {h0, h1, h2, h3};
        half4_t lv = {l0, l1, l2, l3};
        *reinterpret_cast<half4_t*>(&lds[hi_base + off]) = hv;
        *reinterpret_cast<half4_t*>(&lds[lo_base + off]) = lv;
    }
}

__global__ __launch_bounds__(256, 2) void vq_main(const float* __restrict__ z,
                                                  const float* __restrict__ w,
                                                  const float* __restrict__ wsq,
                                                  float* __restrict__ out_zq,
                                                  float* __restrict__ out_idx,
                                                  float* __restrict__ out_loss) {
    __shared__ __align__(16) ushort lds[32768];

    const int t    = threadIdx.x;
    const int lane = t & 63;
    const int wid  = t >> 6;
    const int q    = lane >> 4;          // quad within wave
    const int m15  = lane & 15;
    const int wrow = (wid >> 1) << 5;    // 0 or 32
    const int wcol = (wid & 1) << 5;     // 0 or 32
    const int rowBase = blockIdx.x * BM;

    // ---- stage z tile once (split fp16 hi/lo) ----
    stage_tile(reinterpret_cast<const float4*>(z + (size_t)rowBase * HH),
               lds, ZH, ZL, t);

    float best[2][4];
    int   bidx[2][4];
#pragma unroll
    for (int mt = 0; mt < 2; ++mt)
#pragma unroll
        for (int rg = 0; rg < 4; ++rg) { best[mt][rg] = FLT_MAX; bidx[mt][rg] = 0; }

    const int ar0 = wrow + m15;          // A rows for mt=0 / +16 for mt=1
    const int bn0 = wcol + m15;          // B cols (codes in tile) for nt=0 / +16

    for (int k0 = 0; k0 < KCODES; k0 += BN) {
        __syncthreads();   // z planes ready (1st iter) / prev w consumed
        stage_tile(reinterpret_cast<const float4*>(w + (size_t)k0 * HH),
                   lds, WH, WL, t);
        __syncthreads();

        floatx4 acc[2][2];
#pragma unroll
        for (int mt = 0; mt < 2; ++mt)
#pragma unroll
            for (int nt = 0; nt < 2; ++nt) acc[mt][nt] = (floatx4){0.f, 0.f, 0.f, 0.f};

#pragma unroll
        for (int c = 0; c < 4; ++c) {
            const int hu = (c << 2) + q;   // k = c*32 + q*8 + j  ->  h unit
            half8 zh0 = *reinterpret_cast<half8*>(&lds[ZH + plane_off(ar0,      hu)]);
            half8 zh1 = *reinterpret_cast<half8*>(&lds[ZH + plane_off(ar0 + 16, hu)]);
            half8 zl0 = *reinterpret_cast<half8*>(&lds[ZL + plane_off(ar0,      hu)]);
            half8 zl1 = *reinterpret_cast<half8*>(&lds[ZL + plane_off(ar0 + 16, hu)]);
            half8 wh0 = *reinterpret_cast<half8*>(&lds[WH + plane_off(bn0,      hu)]);
            half8 wh1 = *reinterpret_cast<half8*>(&lds[WH + plane_off(bn0 + 16, hu)]);
            half8 wl0 = *reinterpret_cast<half8*>(&lds[WL + plane_off(bn0,      hu)]);
            half8 wl1 = *reinterpret_cast<half8*>(&lds[WL + plane_off(bn0 + 16, hu)]);
            // dot = zh*wh + zh*wl + zl*wh  (zl*wl term ~2^-22, dropped)
            acc[0][0] = __builtin_amdgcn_mfma_f32_16x16x32_f16(zh0, wh0, acc[0][0], 0, 0, 0);
            acc[0][1] = __builtin_amdgcn_mfma_f32_16x16x32_f16(zh0, wh1, acc[0][1], 0, 0, 0);
            acc[1][0] = __builtin_amdgcn_mfma_f32_16x16x32_f16(zh1, wh0, acc[1][0], 0, 0, 0);
            acc[1][1] = __builtin_amdgcn_mfma_f32_16x16x32_f16(zh1, wh1, acc[1][1], 0, 0, 0);
            acc[0][0] = __builtin_amdgcn_mfma_f32_16x16x32_f16(zh0, wl0, acc[0][0], 0, 0, 0);
            acc[0][1] = __builtin_amdgcn_mfma_f32_16x16x32_f16(zh0, wl1, acc[0][1], 0, 0, 0);
            acc[1][0] = __builtin_amdgcn_mfma_f32_16x16x32_f16(zh1, wl0, acc[1][0], 0, 0, 0);
            acc[1][1] = __builtin_amdgcn_mfma_f32_16x16x32_f16(zh1, wl1, acc[1][1], 0, 0, 0);
            acc[0][0] = __builtin_amdgcn_mfma_f32_16x16x32_f16(zl0, wh0, acc[0][0], 0, 0, 0);
            acc[0][1] = __builtin_amdgcn_mfma_f32_16x16x32_f16(zl0, wh1, acc[0][1], 0, 0, 0);
            acc[1][0] = __builtin_amdgcn_mfma_f32_16x16x32_f16(zl1, wh0, acc[1][0], 0, 0, 0);
            acc[1][1] = __builtin_amdgcn_mfma_f32_16x16x32_f16(zl1, wh1, acc[1][1], 0, 0, 0);
        }

        // scores: d = ||w||^2 - 2*dot ; C/D layout: col=lane&15, row=q*4+reg
        float wq0 = wsq[k0 + bn0];
        float wq1 = wsq[k0 + bn0 + 16];
#pragma unroll
        for (int mt = 0; mt < 2; ++mt) {
#pragma unroll
            for (int nt = 0; nt < 2; ++nt) {
                int   code = k0 + wcol + (nt << 4) + m15;
                float wq = nt ? wq1 : wq0;
#pragma unroll
                for (int rg = 0; rg < 4; ++rg) {
                    float s = fmaf(-2.0f, acc[mt][nt][rg], wq);
                    if (s < best[mt][rg]) { best[mt][rg] = s; bidx[mt][rg] = code; }
                }
            }
        }
    }

    // reduce across the 16 lanes (cols) sharing each row
#pragma unroll
    for (int off = 1; off < 16; off <<= 1) {
#pragma unroll
        for (int mt = 0; mt < 2; ++mt)
#pragma unroll
            for (int rg = 0; rg < 4; ++rg) {
                float os = __shfl_xor(best[mt][rg], off, 64);
                int   oi = __shfl_xor(bidx[mt][rg], off, 64);
                if (os < best[mt][rg] ||
                    (os == best[mt][rg] && oi < bidx[mt][rg])) {
                    best[mt][rg] = os; bidx[mt][rg] = oi;
                }
            }
    }

    // epilogue scratch aliased over the planes (byte offsets):
    //   0:    float epmin[2][64]
    //   512:  int   epidx[2][64]
    //   1024: int   fbidx[64]
    //   1280: float lred[4]
    float* epmin = reinterpret_cast<float*>(lds);
    int*   epidx = reinterpret_cast<int*>(reinterpret_cast<char*>(lds) + 512);
    int*   fbidx = reinterpret_cast<int*>(reinterpret_cast<char*>(lds) + 1024);
    float* lred  = reinterpret_cast<float*>(reinterpret_cast<char*>(lds) + 1280);

    __syncthreads();   // all frag reads done before aliasing
    if (m15 == 0) {
        int grp = wid & 1;
#pragma unroll
        for (int mt = 0; mt < 2; ++mt)
#pragma unroll
            for (int rg = 0; rg < 4; ++rg) {
                int row = wrow + (mt << 4) + (q << 2) + rg;
                epmin[grp * 64 + row] = best[mt][rg];
                epidx[grp * 64 + row] = bidx[mt][rg];
            }
    }
    __syncthreads();

    if (t < BM) {
        float s0 = epmin[t],      s1 = epmin[64 + t];
        int   i0 = epidx[t],      i1 = epidx[64 + t];
        int   fi = (s1 < s0 || (s1 == s0 && i1 < i0)) ? i1 : i0;
        fbidx[t] = fi;
        out_idx[rowBase + t] = (float)fi;
    }
    __syncthreads();

    // gather zq, write out, accumulate loss (z re-read from global, exact)
    const float4* z4 = reinterpret_cast<const float4*>(z);
    float lsum = 0.0f;
#pragma unroll
    for (int i = 0; i < 8; ++i) {
        int g = i * 256 + t;
        int r = g >> 5, f4 = g & 31;
        int code = fbidx[r];
        float4 wv = *reinterpret_cast<const float4*>(w + (size_t)code * HH + (f4 << 2));
        float4 zv = z4[(size_t)(rowBase + r) * 32 + f4];
        float dx = wv.x - zv.x, dy = wv.y - zv.y, dz = wv.z - zv.z, dw = wv.w - zv.w;
        lsum = fmaf(dx, dx, lsum); lsum = fmaf(dy, dy, lsum);
        lsum = fmaf(dz, dz, lsum); lsum = fmaf(dw, dw, lsum);
        *reinterpret_cast<float4*>(out_zq + (size_t)(rowBase + r) * HH + (f4 << 2)) = wv;
    }
#pragma unroll
    for (int off = 1; off < 64; off <<= 1) lsum += __shfl_xor(lsum, off, 64);
    if (lane == 0) lred[wid] = lsum;
    __syncthreads();
    if (t == 0) {
        float total = lred[0] + lred[1] + lred[2] + lred[3];
        // loss = (0.25 + 1.0) * mean((zq - z)^2) over N*H = 4194304 elements
        atomicAdd(out_loss, total * (1.25f / 4194304.0f));
    }
}

extern "C" void kernel_launch(void* const* d_in, const int* in_sizes, int n_in,
                              void* d_out, int out_size, void* d_ws, size_t ws_size,
                              hipStream_t stream) {
    (void)in_sizes; (void)n_in; (void)out_size; (void)ws_size;
    const float* z = (const float*)d_in[0];
    const float* w = (const float*)d_in[1];
    float* out      = (float*)d_out;
    float* out_zq   = out;                                  // N*H
    float* out_idx  = out + (size_t)NROWS * HH;             // N (as float)
    float* out_loss = out + (size_t)NROWS * HH + NROWS;     // 1
    float* wsq = (float*)d_ws;                              // 4096 floats

    vq_prep<<<KCODES / 256, 256, 0, stream>>>(w, wsq, out_loss);
    vq_main<<<NROWS / BM, 256, 0, stream>>>(z, w, wsq, out_zq, out_idx, out_loss);
}

// Round 3
// 178.834 us; speedup vs baseline: 4.6556x; 1.1207x over previous
//
#include <hip/hip_runtime.h>
#include <float.h>
#include <stdint.h>

#define HH 128
#define NROWS 32768
#define KCODES 4096
#define BM 64
#define BN 64
#define NTILES (KCODES / BN)

typedef _Float16 half8 __attribute__((ext_vector_type(8)));
typedef _Float16 half4_t __attribute__((ext_vector_type(4)));
typedef float floatx4 __attribute__((ext_vector_type(4)));
typedef float floatx16 __attribute__((ext_vector_type(16)));
typedef const __attribute__((address_space(1))) uint32_t gbl_u32;
typedef __attribute__((address_space(3))) uint32_t lds_u32;

// Swizzled plane layout (ushort units): unit (r, hu), hu = h/8 in [0,16),
// r = row/code in [0,64). off = (hu*64 + (r ^ (hu&7)))*8. Every 8 consecutive
// r at same hu -> 128 B covering all 32 banks (verified: 0 conflicts in R2).
__device__ __forceinline__ int plane_off(int r, int hu) {
    return ((hu << 6) | (r ^ (hu & 7))) << 3;
}

// ---------------- fast-path prep: wsq + pre-split w into tile planes --------
// 64 blocks x 256. 4 threads per code; thread quarter q handles f4 = q*8..q*8+7.
__global__ __launch_bounds__(256) void vq_prep_split(const float* __restrict__ w,
                                                     float* __restrict__ wsq,
                                                     ushort* __restrict__ whi,
                                                     ushort* __restrict__ wlo,
                                                     float* __restrict__ loss_slot) {
    const int t = threadIdx.x;
    if (blockIdx.x == 0 && t == 0) loss_slot[0] = 0.0f;  // d_out poisoned 0xAA
    const int c = blockIdx.x * 64 + (t >> 2);            // code
    const int q = t & 3;
    const int r = c & 63;
    const size_t tb = (size_t)(c >> 6) * (BN * HH);      // tile base (ushorts)
    const float4* row = reinterpret_cast<const float4*>(w + (size_t)c * HH);
    float s = 0.0f;
#pragma unroll
    for (int i = 0; i < 8; ++i) {
        int f4 = q * 8 + i;
        float4 v = row[f4];
        s = fmaf(v.x, v.x, s); s = fmaf(v.y, v.y, s);
        s = fmaf(v.z, v.z, s); s = fmaf(v.w, v.w, s);
        _Float16 h0 = (_Float16)v.x, h1 = (_Float16)v.y,
                 h2 = (_Float16)v.z, h3 = (_Float16)v.w;
        half4_t hv = {h0, h1, h2, h3};
        half4_t lv = {(_Float16)(v.x - (float)h0), (_Float16)(v.y - (float)h1),
                      (_Float16)(v.z - (float)h2), (_Float16)(v.w - (float)h3)};
        int off = plane_off(r, f4 >> 1) + ((f4 & 1) << 2);
        *reinterpret_cast<half4_t*>(&whi[tb + off]) = hv;
        *reinterpret_cast<half4_t*>(&wlo[tb + off]) = lv;
    }
    s += __shfl_xor(s, 1, 64);
    s += __shfl_xor(s, 2, 64);
    if (q == 0) wsq[c] = s;
}

// ---------------- fast-path main --------------------------------------------
__global__ __launch_bounds__(256, 2) void vq_main_fast(
        const float* __restrict__ z, const float* __restrict__ w,
        const float* __restrict__ wsq,
        const ushort* __restrict__ whi, const ushort* __restrict__ wlo,
        float* __restrict__ out_zq, float* __restrict__ out_idx,
        float* __restrict__ out_loss) {
    // 64 KB: buf0 @0, buf1 @16384 (ushort units); each buf = WH[8192] WL[8192]
    __shared__ __align__(16) ushort lds[32768];

    const int t = threadIdx.x;
    const int lane = t & 63, wid = t >> 6;
    const int col32 = lane & 31, ksel = lane >> 5;
    const int wrow = (wid >> 1) << 5, wcol = (wid & 1) << 5;
    const int rowBase = blockIdx.x * BM;

    // ---- stage z split into buf1 (ZH @16384, ZL @24576) ----
    {
        const float4* zg = reinterpret_cast<const float4*>(z + (size_t)rowBase * HH);
#pragma unroll
        for (int p = 0; p < 8; ++p) {
            int g = p * 256 + t;
            int r = g >> 5, f4 = g & 31;
            float4 v = zg[g];
            _Float16 h0 = (_Float16)v.x, h1 = (_Float16)v.y,
                     h2 = (_Float16)v.z, h3 = (_Float16)v.w;
            half4_t hv = {h0, h1, h2, h3};
            half4_t lv = {(_Float16)(v.x - (float)h0), (_Float16)(v.y - (float)h1),
                          (_Float16)(v.z - (float)h2), (_Float16)(v.w - (float)h3)};
            int off = plane_off(r, f4 >> 1) + ((f4 & 1) << 2);
            *reinterpret_cast<half4_t*>(&lds[16384 + off]) = hv;
            *reinterpret_cast<half4_t*>(&lds[24576 + off]) = lv;
        }
    }

    // ---- per-wave async-copy assignment: plane = wid>>1 (0=hi,1=lo), half = wid&1
    const char* srcPlane = (wid & 2) ? reinterpret_cast<const char*>(wlo)
                                     : reinterpret_cast<const char*>(whi);
    const int halfOffB  = (wid & 1) << 13;                       // bytes in plane
    const int ldsHalfU  = ((wid & 2) << 12) + ((wid & 1) << 12); // ushorts in buf

    auto prefetch = [&](int tile, int buf) {
        const char* src = srcPlane + (size_t)tile * 16384 + halfOffB + (lane << 4);
        ushort* lb = lds + (buf << 14) + ldsHalfU;
#pragma unroll
        for (int p = 0; p < 8; ++p) {
            __builtin_amdgcn_global_load_lds((gbl_u32*)(src + p * 1024),
                                             (lds_u32*)(lb + p * 512), 16, 0, 0);
        }
    };

    prefetch(0, 0);          // tile 0 -> buf0 (no conflict with z in buf1)
    __syncthreads();         // z writes visible (vmcnt(0) also drains tile 0)

    // ---- hoist z fragments (k-invariant A-operands) into registers ----
    half8 zh[8], zl[8];
    {
        const int arow = wrow + col32;
#pragma unroll
        for (int s = 0; s < 8; ++s) {
            int off = plane_off(arow, (s << 1) + ksel);
            zh[s] = *reinterpret_cast<half8*>(&lds[16384 + off]);
            zl[s] = *reinterpret_cast<half8*>(&lds[24576 + off]);
        }
    }
    __syncthreads();         // buf1 free for tile-1 prefetch

    int boff[8];
    {
        const int brow = wcol + col32;
#pragma unroll
        for (int s = 0; s < 8; ++s) boff[s] = plane_off(brow, (s << 1) + ksel);
    }

    float best[16];
    int   bidx[16];
#pragma unroll
    for (int r = 0; r < 16; ++r) { best[r] = FLT_MAX; bidx[r] = 0; }

#pragma unroll 2
    for (int k = 0; k < NTILES; ++k) {
        const int buf = k & 1;
        if (k < NTILES - 1) prefetch(k + 1, buf ^ 1);   // flies during compute
        const int code = (k << 6) + wcol + col32;
        const float wq = wsq[code];                     // L2-hit, issued early
        const ushort* wb = lds + (buf << 14);

        floatx16 acc;
#pragma unroll
        for (int r = 0; r < 16; ++r) acc[r] = 0.0f;
#pragma unroll
        for (int s = 0; s < 8; ++s) {
            half8 wh = *reinterpret_cast<const half8*>(&wb[boff[s]]);
            half8 wl = *reinterpret_cast<const half8*>(&wb[8192 + boff[s]]);
            // dot = zh*wh + zl*wh + zh*wl (zl*wl ~2^-22, dropped)
            acc = __builtin_amdgcn_mfma_f32_32x32x16_f16(zh[s], wh, acc, 0, 0, 0);
            acc = __builtin_amdgcn_mfma_f32_32x32x16_f16(zl[s], wh, acc, 0, 0, 0);
            acc = __builtin_amdgcn_mfma_f32_32x32x16_f16(zh[s], wl, acc, 0, 0, 0);
        }
#pragma unroll
        for (int r = 0; r < 16; ++r) {
            float sc = fmaf(-2.0f, acc[r], wq);
            if (sc < best[r]) { best[r] = sc; bidx[r] = code; }  // strict < = first-min
        }
        __syncthreads();     // tile k consumed; drains tile k+1 (mostly landed)
    }

    // ---- reduce over the 32 cols in each lane half ----
#pragma unroll
    for (int off = 1; off < 32; off <<= 1) {
#pragma unroll
        for (int r = 0; r < 16; ++r) {
            float os = __shfl_xor(best[r], off, 64);
            int   oi = __shfl_xor(bidx[r], off, 64);
            if (os < best[r] || (os == best[r] && oi < bidx[r])) {
                best[r] = os; bidx[r] = oi;
            }
        }
    }

    // epilogue scratch aliased over buf0 (last compute tile was buf1):
    float* epmin = reinterpret_cast<float*>(lds);                                 // [2][64]
    int*   epidx = reinterpret_cast<int*>(reinterpret_cast<char*>(lds) + 512);    // [2][64]
    int*   fbidx = reinterpret_cast<int*>(reinterpret_cast<char*>(lds) + 1024);   // [64]
    float* lred  = reinterpret_cast<float*>(reinterpret_cast<char*>(lds) + 1280); // [4]

    if (col32 == 0) {        // lanes 0 and 32 hold group minima
        int g = wid & 1;
#pragma unroll
        for (int r = 0; r < 16; ++r) {
            // C/D: row = (reg&3) + 8*(reg>>2) + 4*(lane>>5)  [m74/m101]
            int row = wrow + (r & 3) + ((r >> 2) << 3) + (ksel << 2);
            epmin[g * 64 + row] = best[r];
            epidx[g * 64 + row] = bidx[r];
        }
    }
    __syncthreads();

    if (t < BM) {
        float s0 = epmin[t], s1 = epmin[64 + t];
        int   i0 = epidx[t], i1 = epidx[64 + t];
        int   fi = (s1 < s0 || (s1 == s0 && i1 < i0)) ? i1 : i0;
        fbidx[t] = fi;
        out_idx[rowBase + t] = (float)fi;
    }
    __syncthreads();

    // ---- gather zq, write out, loss (z re-read from global, exact fp32) ----
    const float4* z4 = reinterpret_cast<const float4*>(z);
    float lsum = 0.0f;
#pragma unroll
    for (int i = 0; i < 8; ++i) {
        int g = i * 256 + t;
        int r = g >> 5, f4 = g & 31;
        int code = fbidx[r];
        float4 wv = *reinterpret_cast<const float4*>(w + (size_t)code * HH + (f4 << 2));
        float4 zv = z4[(size_t)(rowBase + r) * 32 + f4];
        float dx = wv.x - zv.x, dy = wv.y - zv.y, dz = wv.z - zv.z, dw = wv.w - zv.w;
        lsum = fmaf(dx, dx, lsum); lsum = fmaf(dy, dy, lsum);
        lsum = fmaf(dz, dz, lsum); lsum = fmaf(dw, dw, lsum);
        *reinterpret_cast<float4*>(out_zq + (size_t)(rowBase + r) * HH + (f4 << 2)) = wv;
    }
#pragma unroll
    for (int off = 1; off < 64; off <<= 1) lsum += __shfl_xor(lsum, off, 64);
    if (lane == 0) lred[wid] = lsum;
    __syncthreads();
    if (t == 0) {
        float total = lred[0] + lred[1] + lred[2] + lred[3];
        atomicAdd(out_loss, total * (1.25f / 4194304.0f));  // (0.25+1)*mean, N*H=4194304
    }
}

// ---------------- fallback path (Round-2 kernel, proven 200 us) -------------
__global__ __launch_bounds__(256) void vq_prep_fb(const float* __restrict__ w,
                                                  float* __restrict__ wsq,
                                                  float* __restrict__ loss_slot) {
    int c = blockIdx.x * 256 + threadIdx.x;
    if (c == 0) loss_slot[0] = 0.0f;
    if (c < KCODES) {
        const float4* row = reinterpret_cast<const float4*>(w + (size_t)c * HH);
        float s = 0.0f;
#pragma unroll
        for (int i = 0; i < HH / 4; ++i) {
            float4 v = row[i];
            s = fmaf(v.x, v.x, s); s = fmaf(v.y, v.y, s);
            s = fmaf(v.z, v.z, s); s = fmaf(v.w, v.w, s);
        }
        wsq[c] = s;
    }
}

__device__ __forceinline__ void stage_tile_fb(const float4* __restrict__ src4,
                                              ushort* lds, int hi_base, int lo_base,
                                              int t) {
#pragma unroll
    for (int p = 0; p < 8; ++p) {
        int g = p * 256 + t;
        int r = g >> 5, f4 = g & 31;
        float4 v = src4[g];
        _Float16 h0 = (_Float16)v.x, h1 = (_Float16)v.y,
                 h2 = (_Float16)v.z, h3 = (_Float16)v.w;
        half4_t hv = {h0, h1, h2, h3};
        half4_t lv = {(_Float16)(v.x - (float)h0), (_Float16)(v.y - (float)h1),
                      (_Float16)(v.z - (float)h2), (_Float16)(v.w - (float)h3)};
        int off = plane_off(r, f4 >> 1) + ((f4 & 1) << 2);
        *reinterpret_cast<half4_t*>(&lds[hi_base + off]) = hv;
        *reinterpret_cast<half4_t*>(&lds[lo_base + off]) = lv;
    }
}

__global__ __launch_bounds__(256, 2) void vq_main_fb(const float* __restrict__ z,
                                                     const float* __restrict__ w,
                                                     const float* __restrict__ wsq,
                                                     float* __restrict__ out_zq,
                                                     float* __restrict__ out_idx,
                                                     float* __restrict__ out_loss) {
    __shared__ __align__(16) ushort lds[32768];
    const int t = threadIdx.x, lane = t & 63, wid = t >> 6;
    const int q = lane >> 4, m15 = lane & 15;
    const int wrow = (wid >> 1) << 5, wcol = (wid & 1) << 5;
    const int rowBase = blockIdx.x * BM;

    stage_tile_fb(reinterpret_cast<const float4*>(z + (size_t)rowBase * HH), lds, 0, 8192, t);

    float best[2][4]; int bidx[2][4];
#pragma unroll
    for (int mt = 0; mt < 2; ++mt)
#pragma unroll
        for (int rg = 0; rg < 4; ++rg) { best[mt][rg] = FLT_MAX; bidx[mt][rg] = 0; }

    const int ar0 = wrow + m15, bn0 = wcol + m15;

    for (int k0 = 0; k0 < KCODES; k0 += BN) {
        __syncthreads();
        stage_tile_fb(reinterpret_cast<const float4*>(w + (size_t)k0 * HH), lds, 16384, 24576, t);
        __syncthreads();
        floatx4 acc[2][2];
#pragma unroll
        for (int mt = 0; mt < 2; ++mt)
#pragma unroll
            for (int nt = 0; nt < 2; ++nt) acc[mt][nt] = (floatx4){0.f, 0.f, 0.f, 0.f};
#pragma unroll
        for (int c = 0; c < 4; ++c) {
            const int hu = (c << 2) + q;
            half8 zh0 = *reinterpret_cast<half8*>(&lds[plane_off(ar0, hu)]);
            half8 zh1 = *reinterpret_cast<half8*>(&lds[plane_off(ar0 + 16, hu)]);
            half8 zl0 = *reinterpret_cast<half8*>(&lds[8192 + plane_off(ar0, hu)]);
            half8 zl1 = *reinterpret_cast<half8*>(&lds[8192 + plane_off(ar0 + 16, hu)]);
            half8 wh0 = *reinterpret_cast<half8*>(&lds[16384 + plane_off(bn0, hu)]);
            half8 wh1 = *reinterpret_cast<half8*>(&lds[16384 + plane_off(bn0 + 16, hu)]);
            half8 wl0 = *reinterpret_cast<half8*>(&lds[24576 + plane_off(bn0, hu)]);
            half8 wl1 = *reinterpret_cast<half8*>(&lds[24576 + plane_off(bn0 + 16, hu)]);
            acc[0][0] = __builtin_amdgcn_mfma_f32_16x16x32_f16(zh0, wh0, acc[0][0], 0, 0, 0);
            acc[0][1] = __builtin_amdgcn_mfma_f32_16x16x32_f16(zh0, wh1, acc[0][1], 0, 0, 0);
            acc[1][0] = __builtin_amdgcn_mfma_f32_16x16x32_f16(zh1, wh0, acc[1][0], 0, 0, 0);
            acc[1][1] = __builtin_amdgcn_mfma_f32_16x16x32_f16(zh1, wh1, acc[1][1], 0, 0, 0);
            acc[0][0] = __builtin_amdgcn_mfma_f32_16x16x32_f16(zh0, wl0, acc[0][0], 0, 0, 0);
            acc[0][1] = __builtin_amdgcn_mfma_f32_16x16x32_f16(zh0, wl1, acc[0][1], 0, 0, 0);
            acc[1][0] = __builtin_amdgcn_mfma_f32_16x16x32_f16(zh1, wl0, acc[1][0], 0, 0, 0);
            acc[1][1] = __builtin_amdgcn_mfma_f32_16x16x32_f16(zh1, wl1, acc[1][1], 0, 0, 0);
            acc[0][0] = __builtin_amdgcn_mfma_f32_16x16x32_f16(zl0, wh0, acc[0][0], 0, 0, 0);
            acc[0][1] = __builtin_amdgcn_mfma_f32_16x16x32_f16(zl0, wh1, acc[0][1], 0, 0, 0);
            acc[1][0] = __builtin_amdgcn_mfma_f32_16x16x32_f16(zl1, wh0, acc[1][0], 0, 0, 0);
            acc[1][1] = __builtin_amdgcn_mfma_f32_16x16x32_f16(zl1, wh1, acc[1][1], 0, 0, 0);
        }
        float wq0 = wsq[k0 + bn0], wq1 = wsq[k0 + bn0 + 16];
#pragma unroll
        for (int mt = 0; mt < 2; ++mt)
#pragma unroll
            for (int nt = 0; nt < 2; ++nt) {
                int code = k0 + wcol + (nt << 4) + m15;
                float wq = nt ? wq1 : wq0;
#pragma unroll
                for (int rg = 0; rg < 4; ++rg) {
                    float s = fmaf(-2.0f, acc[mt][nt][rg], wq);
                    if (s < best[mt][rg]) { best[mt][rg] = s; bidx[mt][rg] = code; }
                }
            }
    }
#pragma unroll
    for (int off = 1; off < 16; off <<= 1)
#pragma unroll
        for (int mt = 0; mt < 2; ++mt)
#pragma unroll
            for (int rg = 0; rg < 4; ++rg) {
                float os = __shfl_xor(best[mt][rg], off, 64);
                int   oi = __shfl_xor(bidx[mt][rg], off, 64);
                if (os < best[mt][rg] || (os == best[mt][rg] && oi < bidx[mt][rg])) {
                    best[mt][rg] = os; bidx[mt][rg] = oi;
                }
            }
    float* epmin = reinterpret_cast<float*>(lds);
    int*   epidx = reinterpret_cast<int*>(reinterpret_cast<char*>(lds) + 512);
    int*   fbidx = reinterpret_cast<int*>(reinterpret_cast<char*>(lds) + 1024);
    float* lred  = reinterpret_cast<float*>(reinterpret_cast<char*>(lds) + 1280);
    __syncthreads();
    if (m15 == 0) {
        int g = wid & 1;
#pragma unroll
        for (int mt = 0; mt < 2; ++mt)
#pragma unroll
            for (int rg = 0; rg < 4; ++rg) {
                int row = wrow + (mt << 4) + (q << 2) + rg;
                epmin[g * 64 + row] = best[mt][rg];
                epidx[g * 64 + row] = bidx[mt][rg];
            }
    }
    __syncthreads();
    if (t < BM) {
        float s0 = epmin[t], s1 = epmin[64 + t];
        int   i0 = epidx[t], i1 = epidx[64 + t];
        int   fi = (s1 < s0 || (s1 == s0 && i1 < i0)) ? i1 : i0;
        fbidx[t] = fi;
        out_idx[rowBase + t] = (float)fi;
    }
    __syncthreads();
    const float4* z4 = reinterpret_cast<const float4*>(z);
    float lsum = 0.0f;
#pragma unroll
    for (int i = 0; i < 8; ++i) {
        int g = i * 256 + t;
        int r = g >> 5, f4 = g & 31;
        int code = fbidx[r];
        float4 wv = *reinterpret_cast<const float4*>(w + (size_t)code * HH + (f4 << 2));
        float4 zv = z4[(size_t)(rowBase + r) * 32 + f4];
        float dx = wv.x - zv.x, dy = wv.y - zv.y, dz = wv.z - zv.z, dw = wv.w - zv.w;
        lsum = fmaf(dx, dx, lsum); lsum = fmaf(dy, dy, lsum);
        lsum = fmaf(dz, dz, lsum); lsum = fmaf(dw, dw, lsum);
        *reinterpret_cast<float4*>(out_zq + (size_t)(rowBase + r) * HH + (f4 << 2)) = wv;
    }
#pragma unroll
    for (int off = 1; off < 64; off <<= 1) lsum += __shfl_xor(lsum, off, 64);
    if (lane == 0) lred[wid] = lsum;
    __syncthreads();
    if (t == 0)
        atomicAdd(out_loss, (lred[0] + lred[1] + lred[2] + lred[3]) * (1.25f / 4194304.0f));
}

extern "C" void kernel_launch(void* const* d_in, const int* in_sizes, int n_in,
                              void* d_out, int out_size, void* d_ws, size_t ws_size,
                              hipStream_t stream) {
    (void)in_sizes; (void)n_in; (void)out_size;
    const float* z = (const float*)d_in[0];
    const float* w = (const float*)d_in[1];
    float* out      = (float*)d_out;
    float* out_zq   = out;
    float* out_idx  = out + (size_t)NROWS * HH;
    float* out_loss = out_idx + NROWS;
    float* wsq = (float*)d_ws;

    const size_t WS_NEED = 16384 + 2u * (size_t)(KCODES * HH * 2);  // wsq + whi + wlo
    if (ws_size >= WS_NEED) {
        ushort* whi = (ushort*)((char*)d_ws + 16384);
        ushort* wlo = (ushort*)((char*)d_ws + 16384 + (size_t)KCODES * HH * 2);
        vq_prep_split<<<KCODES / 64, 256, 0, stream>>>(w, wsq, whi, wlo, out_loss);
        vq_main_fast<<<NROWS / BM, 256, 0, stream>>>(z, w, wsq, whi, wlo,
                                                     out_zq, out_idx, out_loss);
    } else {
        vq_prep_fb<<<KCODES / 256, 256, 0, stream>>>(w, wsq, out_loss);
        vq_main_fb<<<NROWS / BM, 256, 0, stream>>>(z, w, wsq, out_zq, out_idx, out_loss);
    }
}